// Round 1
// baseline (1288.456 us; speedup 1.0000x reference)
//
#include <hip/hip_runtime.h>
#include <hip/hip_fp16.h>

typedef _Float16 f16;
typedef __attribute__((ext_vector_type(8))) _Float16 f16x8;
typedef __attribute__((ext_vector_type(4))) float f32x4;

static constexpr int NROWS   = 500000;
static constexpr int NGR     = 4096;
static constexpr int D       = 256;      // D_NODE == D_MOTIF == D_HID
static constexpr int NTILE32 = NROWS / 32;   // 15625 exact
static constexpr int NWAVES  = 2048;         // 256 blocks x 8 waves

// workspace layout (bytes)
static constexpr size_t WS_FRAG_TOP = 0;                 // 131072: W1_top fp16 frags [ct16][kb8][lane64][8]
static constexpr size_t WS_FRAG_BOT = 131072;            // 131072: W1_bot fp16 frags
static constexpr size_t WS_M        = 262144;            // 4096*256*4 = 4 MiB: M = motif@W1_bot + b1
static constexpr size_t WS_FLAG     = 262144 + 4194304;  // 4 B: 1 if batch_indices is int32, 0 if int64

// ---------------------------------------------------------------------------
// K0: pack W1 (fp32 [512][256]) into MFMA B-fragment order, fp16.
// Fragment element: c = ct*16 + (lane&15), k = kb*32 + (lane>>4)*8 + j.
// Also: detect batch_indices element size on-device (sorted, max ~4095).
// ---------------------------------------------------------------------------
__global__ __launch_bounds__(256) void k_prep(const float* __restrict__ W1,
                                              const void* __restrict__ bidx,
                                              void* __restrict__ ws)
{
    int t    = blockIdx.x * 256 + threadIdx.x;   // 0..16383 (two 128KB halves)
    int half = t >> 13;                          // 0 = W1_top, 1 = W1_bot
    int r    = t & 8191;
    int ct   = r >> 9;
    int kb   = (r >> 6) & 7;
    int lane = r & 63;
    int c    = ct * 16 + (lane & 15);
    int k0   = half * 256 + kb * 32 + (lane >> 4) * 8;
    f16x8 v;
#pragma unroll
    for (int j = 0; j < 8; ++j) v[j] = (f16)W1[(size_t)(k0 + j) * D + c];
    ((f16x8*)ws)[t] = v;

    if (t == 0) {
        // Interpret buffer as uint32. If dtype is int64, u[NROWS-1] is the high
        // word of element NROWS/2-1 (in-bounds for both dtypes) and must be 0.
        // If int32, it's the last (max) sorted index ~4095 != 0.
        const unsigned* u = (const unsigned*)bidx;
        *(int*)((char*)ws + WS_FLAG) = (u[NROWS - 1] != 0u) ? 1 : 0;
    }
}

// ---------------------------------------------------------------------------
// K1: M[g][c] = sum_k motif[g][k] * W1_bot[k][c] + b1[c]   (fp16 MFMA)
// 32 blocks x 8 waves = 256 waves, one 16-row tile each (4096 rows).
// ---------------------------------------------------------------------------
__global__ __launch_bounds__(512) void k_motif(const float* __restrict__ motif,
                                               const float* __restrict__ b1,
                                               void* __restrict__ ws)
{
    extern __shared__ char lds_raw[];
    {
        const float4* src = (const float4*)((const char*)ws + WS_FRAG_BOT);
        float4* dst = (float4*)lds_raw;
        for (int i = threadIdx.x; i < 8192; i += 512) dst[i] = src[i];
    }
    __syncthreads();
    const f16x8* fr = (const f16x8*)lds_raw;
    float* M = (float*)((char*)ws + WS_M);

    int wave = blockIdx.x * 8 + (threadIdx.x >> 6);   // 0..255
    int lane = threadIdx.x & 63;
    int cidx = lane & 15, gidx = lane >> 4;
    int r0 = wave * 16;

    f16x8 af[8];
#pragma unroll
    for (int kb = 0; kb < 8; ++kb) {
        const float* p = motif + (size_t)(r0 + cidx) * D + kb * 32 + gidx * 8;
        float4 x = *(const float4*)p;
        float4 y = *(const float4*)(p + 4);
        f16x8 v;
        v[0]=(f16)x.x; v[1]=(f16)x.y; v[2]=(f16)x.z; v[3]=(f16)x.w;
        v[4]=(f16)y.x; v[5]=(f16)y.y; v[6]=(f16)y.z; v[7]=(f16)y.w;
        af[kb] = v;
    }
#pragma unroll
    for (int ct = 0; ct < 16; ++ct) {
        float b1c = b1[ct * 16 + cidx];
        f32x4 acc = {b1c, b1c, b1c, b1c};
#pragma unroll
        for (int kb = 0; kb < 8; ++kb)
            acc = __builtin_amdgcn_mfma_f32_16x16x32_f16(af[kb], fr[(ct*8 + kb)*64 + lane], acc, 0, 0, 0);
        int col = ct * 16 + cidx;
        int rb  = r0 + gidx * 4;
#pragma unroll
        for (int reg = 0; reg < 4; ++reg)
            M[(size_t)(rb + reg) * D + col] = acc[reg];
    }
}

// ---------------------------------------------------------------------------
// K2: out[r] = sigmoid( sum_c relu( node[r]@W1_top[:,c] + M[g(r)][c] ) * W2[c] + b2 )
// 256 blocks x 512 thr. W1_top frags resident in LDS (128 KB, staged once).
// Each wave: 32 rows (2x16), A-frags in regs, B-frag ds_read_b128 shared
// across the two row-tiles, fused relu/W2-dot/sigmoid epilogue.
// ---------------------------------------------------------------------------
__global__ __launch_bounds__(512) void k_main(const float* __restrict__ A,
                                              const void* __restrict__ bidx,
                                              const float* __restrict__ W2,
                                              const float* __restrict__ b2,
                                              const void* __restrict__ ws,
                                              float* __restrict__ out)
{
    extern __shared__ char lds_raw[];
    {
        const float4* src = (const float4*)((const char*)ws + WS_FRAG_TOP);
        float4* dst = (float4*)lds_raw;
        for (int i = threadIdx.x; i < 8192; i += 512) dst[i] = src[i];
    }
    __syncthreads();
    const f16x8* fr = (const f16x8*)lds_raw;
    const float* M  = (const float*)((const char*)ws + WS_M);
    const int flag32 = *(const int*)((const char*)ws + WS_FLAG);
    const int* b32 = (const int*)bidx;
    const long long* b64 = (const long long*)bidx;

    int lane  = threadIdx.x & 63;
    int cidx  = lane & 15, gidx = lane >> 4;
    int gwave = blockIdx.x * 8 + (threadIdx.x >> 6);  // 0..2047

    float w2v[16];
#pragma unroll
    for (int ct = 0; ct < 16; ++ct) w2v[ct] = W2[ct * 16 + cidx];
    float b2v = b2[0];

    for (int tile = gwave; tile < NTILE32; tile += NWAVES) {
        int r0 = tile * 32;
        // graph id for row r0 + (lane&31); sorted -> usually wave-uniform
        int gl = flag32 ? b32[r0 + (lane & 31)] : (int)b64[r0 + (lane & 31)];
        int g0 = __builtin_amdgcn_readfirstlane(gl);
        bool uni = (__all(gl == g0) != 0);

        // A fragments: rows r0 + t*16 + cidx, k = kb*32 + gidx*8 + j (fp32 -> fp16)
        f16x8 af[2][8];
#pragma unroll
        for (int t = 0; t < 2; ++t)
#pragma unroll
        for (int kb = 0; kb < 8; ++kb) {
            const float* p = A + (size_t)(r0 + t*16 + cidx) * D + kb*32 + gidx*8;
            float4 x = *(const float4*)p;
            float4 y = *(const float4*)(p + 4);
            f16x8 v;
            v[0]=(f16)x.x; v[1]=(f16)x.y; v[2]=(f16)x.z; v[3]=(f16)x.w;
            v[4]=(f16)y.x; v[5]=(f16)y.y; v[6]=(f16)y.z; v[7]=(f16)y.w;
            af[t][kb] = v;
        }

        float mv[16];
        if (uni) {
            const float* Mg = M + (size_t)g0 * D;
#pragma unroll
            for (int ct = 0; ct < 16; ++ct) mv[ct] = Mg[ct * 16 + cidx];
        }

        float rs0[4] = {0.f,0.f,0.f,0.f};
        float rs1[4] = {0.f,0.f,0.f,0.f};

#pragma unroll
        for (int ct = 0; ct < 16; ++ct) {
            f32x4 acc0, acc1;
            if (uni) {
                float m = mv[ct];
                acc0 = (f32x4){m, m, m, m};
                acc1 = acc0;
            } else {
#pragma unroll
                for (int reg = 0; reg < 4; ++reg) {
                    int rr = gidx * 4 + reg;
                    int ga = __shfl(gl, rr);
                    int gb = __shfl(gl, 16 + rr);
                    acc0[reg] = M[(size_t)ga * D + ct*16 + cidx];
                    acc1[reg] = M[(size_t)gb * D + ct*16 + cidx];
                }
            }
#pragma unroll
            for (int kb = 0; kb < 8; ++kb) {
                f16x8 bf = fr[(ct*8 + kb)*64 + lane];   // lane-contiguous: conflict-free
                acc0 = __builtin_amdgcn_mfma_f32_16x16x32_f16(af[0][kb], bf, acc0, 0, 0, 0);
                acc1 = __builtin_amdgcn_mfma_f32_16x16x32_f16(af[1][kb], bf, acc1, 0, 0, 0);
            }
            float w2c = w2v[ct];
#pragma unroll
            for (int reg = 0; reg < 4; ++reg) {
                rs0[reg] += fmaxf(acc0[reg], 0.f) * w2c;
                rs1[reg] += fmaxf(acc1[reg], 0.f) * w2c;
            }
        }
        // reduce the 16 column-partials (lanes sharing gidx) per row
#pragma unroll
        for (int msk = 1; msk <= 8; msk <<= 1) {
#pragma unroll
            for (int reg = 0; reg < 4; ++reg) {
                rs0[reg] += __shfl_xor(rs0[reg], msk);
                rs1[reg] += __shfl_xor(rs1[reg], msk);
            }
        }
        if (cidx < 4) {
            float v0 = cidx==0 ? rs0[0] : cidx==1 ? rs0[1] : cidx==2 ? rs0[2] : rs0[3];
            float v1 = cidx==0 ? rs1[0] : cidx==1 ? rs1[1] : cidx==2 ? rs1[2] : rs1[3];
            int rbase = r0 + gidx * 4 + cidx;
            out[rbase]      = 1.f / (1.f + __expf(-(v0 + b2v)));
            out[rbase + 16] = 1.f / (1.f + __expf(-(v1 + b2v)));
        }
    }
}

extern "C" void kernel_launch(void* const* d_in, const int* in_sizes, int n_in,
                              void* d_out, int out_size, void* d_ws, size_t ws_size,
                              hipStream_t stream)
{
    (void)in_sizes; (void)n_in; (void)out_size; (void)ws_size;
    const float* node  = (const float*)d_in[0];
    const float* motif = (const float*)d_in[1];
    const void*  bidx  = d_in[2];
    const float* W1    = (const float*)d_in[3];
    const float* b1    = (const float*)d_in[4];
    const float* W2    = (const float*)d_in[5];
    const float* b2    = (const float*)d_in[6];
    float* out = (float*)d_out;

    // allow 128 KiB dynamic LDS (idempotent; not a stream op, capture-safe)
    hipFuncSetAttribute((const void*)k_motif, hipFuncAttributeMaxDynamicSharedMemorySize, 131072);
    hipFuncSetAttribute((const void*)k_main,  hipFuncAttributeMaxDynamicSharedMemorySize, 131072);

    k_prep <<<64, 256, 0, stream>>>(W1, bidx, d_ws);
    k_motif<<<32, 512, 131072, stream>>>(motif, b1, d_ws);
    k_main <<<256, 512, 131072, stream>>>(node, bidx, W2, b2, d_ws, out);
}